// Round 8
// baseline (429.069 us; speedup 1.0000x reference)
//
#include <hip/hip_runtime.h>

#define B 8
#define NF 4096
#define NT 4096
#define D_HID 128
#define D_OUT 32
#define D_V 16
#define TILE_I 64

__device__ inline float fast_exp2(float x) {
#if __has_builtin(__builtin_amdgcn_exp2f)
  return __builtin_amdgcn_exp2f(x);
#else
  return exp2f(x);
#endif
}

// ---------------- MLP: [N,3] -> relu(x W1 + b1) W2 + b2 -> [N,32] ----------------
__global__ __launch_bounds__(64) void mlp_kernel(
    const float* __restrict__ x, const float* __restrict__ W1,
    const float* __restrict__ b1, const float* __restrict__ W2,
    const float* __restrict__ b2, float* __restrict__ out) {
  __shared__ float sW1[3 * D_HID];
  __shared__ float sb1[D_HID];
  __shared__ float sW2[D_HID * D_OUT];
  __shared__ float sb2[D_OUT];
  const int tid = threadIdx.x;
  for (int idx = tid; idx < D_HID * D_OUT; idx += 64) sW2[idx] = W2[idx];
  for (int idx = tid; idx < 3 * D_HID; idx += 64) sW1[idx] = W1[idx];
  for (int idx = tid; idx < D_HID; idx += 64) sb1[idx] = b1[idx];
  if (tid < D_OUT) sb2[tid] = b2[tid];
  __syncthreads();

  const int t = blockIdx.x * 64 + tid;
  const float x0 = x[t * 3 + 0];
  const float x1 = x[t * 3 + 1];
  const float x2 = x[t * 3 + 2];
  float acc[D_OUT];
#pragma unroll
  for (int o = 0; o < D_OUT; ++o) acc[o] = sb2[o];
#pragma unroll 4
  for (int h = 0; h < D_HID; ++h) {
    float hv = fmaf(x2, sW1[2 * D_HID + h],
               fmaf(x1, sW1[1 * D_HID + h],
               fmaf(x0, sW1[0 * D_HID + h], sb1[h])));
    hv = fmaxf(hv, 0.0f);
    const float4* w2r = reinterpret_cast<const float4*>(&sW2[h * D_OUT]);
#pragma unroll
    for (int o4 = 0; o4 < D_OUT / 4; ++o4) {
      const float4 w = w2r[o4];
      acc[o4 * 4 + 0] = fmaf(hv, w.x, acc[o4 * 4 + 0]);
      acc[o4 * 4 + 1] = fmaf(hv, w.y, acc[o4 * 4 + 1]);
      acc[o4 * 4 + 2] = fmaf(hv, w.z, acc[o4 * 4 + 2]);
      acc[o4 * 4 + 3] = fmaf(hv, w.w, acc[o4 * 4 + 3]);
    }
  }
  float* op = out + (size_t)t * D_OUT;
#pragma unroll
  for (int o = 0; o < D_OUT; o += 4) {
    float4 w = make_float4(acc[o], acc[o + 1], acc[o + 2], acc[o + 3]);
    *reinterpret_cast<float4*>(op + o) = w;
  }
}

// ------------- fused L1-dist + softmax(over i) + PV, flash style over NF -------------
// Same structure as r7 (2 j-slots, LDS tiles), but register-dieted to avoid spill:
// K read in two 4xfloat4 halves (16 live regs), V JIT after dist (8 live regs).
// Liveness ~155 <= 168 cap -> no scratch spill (r7 allocated exactly at cap = spilled).
__global__ __launch_bounds__(256, 3) void attn_kernel(
    const float* __restrict__ Wk, const float* __restrict__ Wq,
    const float* __restrict__ Vf, float* __restrict__ partial,
    int nchunks, int chlen) {
  // per buffer: K tile 64x32 = 512 float4, V tile 64x16 = 256 float4 -> 12 KB
  __shared__ float4 sTile[2][768];
  const int tid = threadIdx.x;
  const int j0 = blockIdx.x * 512 + tid;   // slot 0
  const int j1 = j0 + 256;                 // slot 1 (coalesced with slot 0)
  const int b = blockIdx.y;
  const int c = blockIdx.z;
  const int i0 = c * chlen;
  const int ntiles = chlen / TILE_I;

  float q[2][D_OUT];
  {
    const float* qp0 = Wq + ((size_t)b * NT + j0) * D_OUT;
    const float* qp1 = Wq + ((size_t)b * NT + j1) * D_OUT;
#pragma unroll
    for (int d = 0; d < D_OUT; d += 4) {
      float4 t4 = *reinterpret_cast<const float4*>(qp0 + d);
      q[0][d + 0] = t4.x; q[0][d + 1] = t4.y; q[0][d + 2] = t4.z; q[0][d + 3] = t4.w;
      float4 u4 = *reinterpret_cast<const float4*>(qp1 + d);
      q[1][d + 0] = u4.x; q[1][d + 1] = u4.y; q[1][d + 2] = u4.z; q[1][d + 3] = u4.w;
    }
  }

  constexpr float C2 = -0.72134752044448170368f;  // -log2(e)/2

  float m0 = -1e30f, m1 = -1e30f;  // running max, log2 domain
  float l0 = 0.0f, l1 = 0.0f;
  float acc[2][D_V];
#pragma unroll
  for (int s = 0; s < 2; ++s)
#pragma unroll
    for (int k = 0; k < D_V; ++k) acc[s][k] = 0.0f;

  const float4* gK4 = reinterpret_cast<const float4*>(Wk + ((size_t)b * NF + i0) * D_OUT);
  const float4* gV4 = reinterpret_cast<const float4*>(Vf + ((size_t)b * NF + i0) * D_V);

  // prologue: stage tile 0 into buf 0
  {
    float4 f0 = gK4[tid];
    float4 f1 = gK4[256 + tid];
    float4 f2 = gV4[tid];
    sTile[0][tid] = f0;
    sTile[0][256 + tid] = f1;
    sTile[0][512 + tid] = f2;
  }
  __syncthreads();

  for (int t = 0; t < ntiles; ++t) {
    const int cur = t & 1;
    float4 f0, f1, f2;
    const bool more = (t + 1 < ntiles);
    if (more) {  // issue next tile's loads; they fly during the 64-row compute
      f0 = gK4[(size_t)(t + 1) * 512 + tid];
      f1 = gK4[(size_t)(t + 1) * 512 + 256 + tid];
      f2 = gV4[(size_t)(t + 1) * 256 + tid];
    }
    const float4* kb4 = &sTile[cur][0];
    const float4* vb4 = &sTile[cur][512];
    for (int r = 0; r < TILE_I; ++r) {
      // ---- K half 1: dims 0..15 ----
      const float4 k0 = kb4[0];
      const float4 k1 = kb4[1];
      const float4 k2 = kb4[2];
      const float4 k3 = kb4[3];
      float a0 = fabsf(k0.x - q[0][0]);
      float b0 = fabsf(k0.x - q[1][0]);
      float a1 = fabsf(k0.y - q[0][1]);
      float b1 = fabsf(k0.y - q[1][1]);
      float a2 = fabsf(k0.z - q[0][2]);
      float b2 = fabsf(k0.z - q[1][2]);
      float a3 = fabsf(k0.w - q[0][3]);
      float b3 = fabsf(k0.w - q[1][3]);
      a0 += fabsf(k1.x - q[0][4]);  b0 += fabsf(k1.x - q[1][4]);
      a1 += fabsf(k1.y - q[0][5]);  b1 += fabsf(k1.y - q[1][5]);
      a2 += fabsf(k1.z - q[0][6]);  b2 += fabsf(k1.z - q[1][6]);
      a3 += fabsf(k1.w - q[0][7]);  b3 += fabsf(k1.w - q[1][7]);
      a0 += fabsf(k2.x - q[0][8]);  b0 += fabsf(k2.x - q[1][8]);
      a1 += fabsf(k2.y - q[0][9]);  b1 += fabsf(k2.y - q[1][9]);
      a2 += fabsf(k2.z - q[0][10]); b2 += fabsf(k2.z - q[1][10]);
      a3 += fabsf(k2.w - q[0][11]); b3 += fabsf(k2.w - q[1][11]);
      a0 += fabsf(k3.x - q[0][12]); b0 += fabsf(k3.x - q[1][12]);
      a1 += fabsf(k3.y - q[0][13]); b1 += fabsf(k3.y - q[1][13]);
      a2 += fabsf(k3.z - q[0][14]); b2 += fabsf(k3.z - q[1][14]);
      a3 += fabsf(k3.w - q[0][15]); b3 += fabsf(k3.w - q[1][15]);
      // ---- K half 2: dims 16..31 (k0..k3 regs recycled) ----
      const float4 k4 = kb4[4];
      const float4 k5 = kb4[5];
      const float4 k6 = kb4[6];
      const float4 k7 = kb4[7];
      kb4 += 8;
      a0 += fabsf(k4.x - q[0][16]); b0 += fabsf(k4.x - q[1][16]);
      a1 += fabsf(k4.y - q[0][17]); b1 += fabsf(k4.y - q[1][17]);
      a2 += fabsf(k4.z - q[0][18]); b2 += fabsf(k4.z - q[1][18]);
      a3 += fabsf(k4.w - q[0][19]); b3 += fabsf(k4.w - q[1][19]);
      a0 += fabsf(k5.x - q[0][20]); b0 += fabsf(k5.x - q[1][20]);
      a1 += fabsf(k5.y - q[0][21]); b1 += fabsf(k5.y - q[1][21]);
      a2 += fabsf(k5.z - q[0][22]); b2 += fabsf(k5.z - q[1][22]);
      a3 += fabsf(k5.w - q[0][23]); b3 += fabsf(k5.w - q[1][23]);
      a0 += fabsf(k6.x - q[0][24]); b0 += fabsf(k6.x - q[1][24]);
      a1 += fabsf(k6.y - q[0][25]); b1 += fabsf(k6.y - q[1][25]);
      a2 += fabsf(k6.z - q[0][26]); b2 += fabsf(k6.z - q[1][26]);
      a3 += fabsf(k6.w - q[0][27]); b3 += fabsf(k6.w - q[1][27]);
      a0 += fabsf(k7.x - q[0][28]); b0 += fabsf(k7.x - q[1][28]);
      a1 += fabsf(k7.y - q[0][29]); b1 += fabsf(k7.y - q[1][29]);
      a2 += fabsf(k7.z - q[0][30]); b2 += fabsf(k7.z - q[1][30]);
      a3 += fabsf(k7.w - q[0][31]); b3 += fabsf(k7.w - q[1][31]);
      const float dist0 = (a0 + a1) + (a2 + a3);
      const float dist1 = (b0 + b1) + (b2 + b3);

      const float d20 = dist0 * dist0;
      const float d21 = dist1 * dist1;
      float parg0 = fmaf(C2, d20, -m0);
      float parg1 = fmaf(C2, d21, -m1);
      if (__any(fmaxf(parg0, parg1) > 4.0f)) {  // rare, wave-uniform rescale
        const float s20 = C2 * d20;
        const float mn0 = fmaxf(m0, s20);
        const float al0 = fast_exp2(m0 - mn0);
        l0 *= al0;
#pragma unroll
        for (int k = 0; k < D_V; ++k) acc[0][k] *= al0;
        m0 = mn0;
        parg0 = s20 - mn0;
        const float s21 = C2 * d21;
        const float mn1 = fmaxf(m1, s21);
        const float al1 = fast_exp2(m1 - mn1);
        l1 *= al1;
#pragma unroll
        for (int k = 0; k < D_V; ++k) acc[1][k] *= al1;
        m1 = mn1;
        parg1 = s21 - mn1;
      }
      const float p0 = fast_exp2(parg0);
      const float p1 = fast_exp2(parg1);
      l0 += p0;
      l1 += p1;

      // ---- V JIT in two halves (8 live regs) ----
      {
        const float4 v0 = vb4[0];
        const float4 v1 = vb4[1];
        acc[0][0]  = fmaf(p0, v0.x, acc[0][0]);   acc[1][0]  = fmaf(p1, v0.x, acc[1][0]);
        acc[0][1]  = fmaf(p0, v0.y, acc[0][1]);   acc[1][1]  = fmaf(p1, v0.y, acc[1][1]);
        acc[0][2]  = fmaf(p0, v0.z, acc[0][2]);   acc[1][2]  = fmaf(p1, v0.z, acc[1][2]);
        acc[0][3]  = fmaf(p0, v0.w, acc[0][3]);   acc[1][3]  = fmaf(p1, v0.w, acc[1][3]);
        acc[0][4]  = fmaf(p0, v1.x, acc[0][4]);   acc[1][4]  = fmaf(p1, v1.x, acc[1][4]);
        acc[0][5]  = fmaf(p0, v1.y, acc[0][5]);   acc[1][5]  = fmaf(p1, v1.y, acc[1][5]);
        acc[0][6]  = fmaf(p0, v1.z, acc[0][6]);   acc[1][6]  = fmaf(p1, v1.z, acc[1][6]);
        acc[0][7]  = fmaf(p0, v1.w, acc[0][7]);   acc[1][7]  = fmaf(p1, v1.w, acc[1][7]);
      }
      {
        const float4 v2 = vb4[2];
        const float4 v3 = vb4[3];
        vb4 += 4;
        acc[0][8]  = fmaf(p0, v2.x, acc[0][8]);   acc[1][8]  = fmaf(p1, v2.x, acc[1][8]);
        acc[0][9]  = fmaf(p0, v2.y, acc[0][9]);   acc[1][9]  = fmaf(p1, v2.y, acc[1][9]);
        acc[0][10] = fmaf(p0, v2.z, acc[0][10]);  acc[1][10] = fmaf(p1, v2.z, acc[1][10]);
        acc[0][11] = fmaf(p0, v2.w, acc[0][11]);  acc[1][11] = fmaf(p1, v2.w, acc[1][11]);
        acc[0][12] = fmaf(p0, v3.x, acc[0][12]);  acc[1][12] = fmaf(p1, v3.x, acc[1][12]);
        acc[0][13] = fmaf(p0, v3.y, acc[0][13]);  acc[1][13] = fmaf(p1, v3.y, acc[1][13]);
        acc[0][14] = fmaf(p0, v3.z, acc[0][14]);  acc[1][14] = fmaf(p1, v3.z, acc[1][14]);
        acc[0][15] = fmaf(p0, v3.w, acc[0][15]);  acc[1][15] = fmaf(p1, v3.w, acc[1][15]);
      }
    }
    if (more) {  // write-late: loads long since landed
      const int nxt = cur ^ 1;
      sTile[nxt][tid] = f0;
      sTile[nxt][256 + tid] = f1;
      sTile[nxt][512 + tid] = f2;
    }
    __syncthreads();
  }

  // SoA partials: partial[f * (nchunks*B*NT) + (c*B + b)*NT + j] -> coalesced
  const size_t fstride = (size_t)nchunks * B * NT;
  float* ps0 = partial + ((size_t)c * B + b) * NT + j0;
  float* ps1 = partial + ((size_t)c * B + b) * NT + j1;
  ps0[0] = m0;
  ps1[0] = m1;
  ps0[fstride] = l0;
  ps1[fstride] = l1;
#pragma unroll
  for (int k = 0; k < D_V; ++k) {
    ps0[(size_t)(2 + k) * fstride] = acc[0][k];
    ps1[(size_t)(2 + k) * fstride] = acc[1][k];
  }
}

// ---------------- combine NF-chunk partials -> output ----------------
__global__ __launch_bounds__(256) void combine_kernel(
    const float* __restrict__ partial, float* __restrict__ out, int nchunks) {
  const int t = blockIdx.x * 256 + threadIdx.x;  // = b*NT + j
  const size_t fstride = (size_t)nchunks * B * NT;
  float M = -1e30f;
  for (int c = 0; c < nchunks; ++c)
    M = fmaxf(M, partial[(size_t)c * (B * NT) + t]);
  float L = 0.0f;
  float acc[D_V];
#pragma unroll
  for (int k = 0; k < D_V; ++k) acc[k] = 0.0f;
  for (int c = 0; c < nchunks; ++c) {
    const size_t base = (size_t)c * (B * NT) + t;
    const float w = fast_exp2(partial[base] - M);
    L = fmaf(w, partial[fstride + base], L);
#pragma unroll
    for (int k = 0; k < D_V; ++k)
      acc[k] = fmaf(w, partial[(size_t)(2 + k) * fstride + base], acc[k]);
  }
  const float inv = 1.0f / L;
  float* op = out + (size_t)t * D_V;
#pragma unroll
  for (int k = 0; k < D_V; ++k) op[k] = acc[k] * inv;
}

extern "C" void kernel_launch(void* const* d_in, const int* in_sizes, int n_in,
                              void* d_out, int out_size, void* d_ws, size_t ws_size,
                              hipStream_t stream) {
  const float* coords_f = (const float*)d_in[0];
  const float* values_f = (const float*)d_in[1];
  const float* coords_t = (const float*)d_in[2];
  const float* Wk1 = (const float*)d_in[3];
  const float* bk1 = (const float*)d_in[4];
  const float* Wk2 = (const float*)d_in[5];
  const float* bk2 = (const float*)d_in[6];
  const float* Wq1 = (const float*)d_in[7];
  const float* bq1 = (const float*)d_in[8];
  const float* Wq2 = (const float*)d_in[9];
  const float* bq2 = (const float*)d_in[10];
  float* out = (float*)d_out;

  float* Wk = (float*)d_ws;                        // 4 MB
  float* Wq = Wk + (size_t)B * NF * D_OUT;         // 4 MB
  float* partial = Wq + (size_t)B * NT * D_OUT;

  const size_t fixed = (size_t)(B * NF * D_OUT + B * NT * D_OUT) * sizeof(float);
  int nchunks = 32;  // chlen = 128 = 2 tiles of 64
  while (nchunks > 1 &&
         fixed + (size_t)B * NT * nchunks * 18 * sizeof(float) > ws_size)
    nchunks >>= 1;
  const int chlen = NF / nchunks;

  hipLaunchKernelGGL(mlp_kernel, dim3(B * NF / 64), dim3(64), 0, stream,
                     coords_f, Wk1, bk1, Wk2, bk2, Wk);
  hipLaunchKernelGGL(mlp_kernel, dim3(B * NT / 64), dim3(64), 0, stream,
                     coords_t, Wq1, bq1, Wq2, bq2, Wq);
  hipLaunchKernelGGL(attn_kernel, dim3(NT / 512, B, nchunks), dim3(256), 0, stream,
                     Wk, Wq, values_f, partial, nchunks, chlen);
  hipLaunchKernelGGL(combine_kernel, dim3(B * NT / 256), dim3(256), 0, stream,
                     partial, out, nchunks);
}